// Round 15
// baseline (840.194 us; speedup 1.0000x reference)
//
#include <hip/hip_runtime.h>
#include <math.h>

#define H 64
#define VOCABN 64
#define LSEQ 2048
#define LN_EPS 1e-5f

// ---------- generic DPP add helper ----------
template <int CTRL>
__device__ __forceinline__ float dpp_add(float x) {
  return x + __int_as_float(__builtin_amdgcn_update_dpp(
      0, __float_as_int(x), CTRL, 0xF, 0xF, true));
}

// all-lane sum with broadcast result (tables / readout only)
__device__ __forceinline__ float wave_allsum(float x) {
  x = dpp_add<0xB1>(x);   // quad_perm [1,0,3,2]
  x = dpp_add<0x4E>(x);   // quad_perm [2,3,0,1]
  x = dpp_add<0x141>(x);  // row_half_mirror
  x = dpp_add<0x140>(x);  // row_mirror
  x += __shfl_xor(x, 16, 64);
  x += __shfl_xor(x, 32, 64);
  return x;
}

// all-VALU wave64 reduction: lane 63 holds the total (rounds 3/7-14 validated)
__device__ __forceinline__ float reduce_to_lane63(float x) {
  x = dpp_add<0x111>(x);  // row_shr:1
  x = dpp_add<0x112>(x);  // row_shr:2
  x = dpp_add<0x114>(x);  // row_shr:4
  x = dpp_add<0x118>(x);  // row_shr:8
  x = dpp_add<0x142>(x);  // row_bcast:15
  x = dpp_add<0x143>(x);  // row_bcast:31
  return x;
}

// norm (sqrt of wave-total of x*x), uniform via readlane 63 (same bits as rounds 10-14)
__device__ __forceinline__ float wave_norm63(float x) {
  float nd2 = reduce_to_lane63(x * x);
  return sqrtf(__int_as_float(__builtin_amdgcn_readlane(__float_as_int(nd2), 63)));
}

// ---------------- Kernel A: per-token tables (verbatim rounds 7-14, passed) ----------------
__global__ __launch_bounds__(64) void tables_kernel(
    const float* __restrict__ embed, const float* __restrict__ W1, const float* __restrict__ b1,
    const float* __restrict__ W2, const float* __restrict__ b2,
    const float* __restrict__ ln_g, const float* __restrict__ ln_b,
    const float* __restrict__ Wk, const float* __restrict__ Wv,
    float* __restrict__ Htab, float* __restrict__ Ktab, float* __restrict__ Vtab,
    float* __restrict__ nvtab)
{
  __shared__ float hs[H];
  __shared__ float ff1[2 * H];
  __shared__ float lns[H];
  const int c = blockIdx.x;
  const int i = threadIdx.x;

  float e = embed[c * H + i];
  hs[i] = e;
  __syncthreads();

  float r1 = b1[i], r2 = b1[i + H];
  for (int j = 0; j < H; ++j) {
    float hj = hs[j];
    r1 = fmaf(W1[i * H + j], hj, r1);
    r2 = fmaf(W1[(i + H) * H + j], hj, r2);
  }
  ff1[i]     = fmaxf(r1, 0.f);
  ff1[i + H] = fmaxf(r2, 0.f);
  __syncthreads();

  float o = b2[i];
  for (int m = 0; m < 2 * H; ++m) o = fmaf(W2[i * 2 * H + m], ff1[m], o);
  float y = e + o;

  float mu  = wave_allsum(y) * (1.f / H);
  float d   = y - mu;
  float var = wave_allsum(d * d) * (1.f / H);
  float ln  = d * (1.f / sqrtf(var + LN_EPS)) * ln_g[i] + ln_b[i];
  lns[i] = ln;
  __syncthreads();
  Htab[c * H + i] = ln;

  float k = 0.f, v = 0.f;
  for (int j = 0; j < H; ++j) {
    float lj = lns[j];
    k = fmaf(Wk[i * H + j], lj, k);
    v = fmaf(Wv[i * H + j], lj, v);
  }
  float nk = sqrtf(wave_allsum(k * k));
  Ktab[c * H + i] = k / fmaxf(nk, 1e-12f);
  Vtab[c * H + i] = v;
  float nv = sqrtf(wave_allsum(v * v));
  if (i == 0) nvtab[c] = 0.4f * nv;   // gate threshold, sqrt domain
}

// ---------------- Kernel B: 8-wave eager scan, prefetched slices, pipelined norms ----------------
// One block (8 waves) per batch element. R in LDS, in-place RMW split 8 rows/wave,
// M column-split 8 cols/wave. Round-13 two-barrier discipline (read-fence+write-fence).
// G/K row slices prefetched one step early (static tables, race-free). Norm of each
// pipeline row computed at entry (3 steps slack); recomputed only for forwarded rows
// on accepts. All gate values / deltas / M bitwise identical to rounds 10-14.
__global__ __launch_bounds__(512, 1) void scan_kernel(
    const int* __restrict__ x, const float* __restrict__ Htab,
    const float* __restrict__ Ktab, const float* __restrict__ Vtab,
    const float* __restrict__ nvtab,
    const float* __restrict__ Wq, const float* __restrict__ Wr,
    const float* __restrict__ alpha, const float* __restrict__ Wout,
    const float* __restrict__ bout, float* __restrict__ out)
{
  __shared__ float4 Kl4[VOCABN * H / 4];   // khat [c][j]; becomes M_N after scan
  __shared__ float4 Vl4[VOCABN * H / 4];   // v [c][i];   becomes M_T after scan
  __shared__ float4 Gl4[VOCABN * H / 4];   // Gram [c][cc] (static after init)
  __shared__ float4 Rl4[VOCABN * H / 4];   // residual [c][i]
  __shared__ int4   xl4[LSEQ / 4];
  __shared__ float  thl[VOCABN];           // 0.4*||v||
  __shared__ float  hbuf[H];
  __shared__ float  qbuf[H];
  __shared__ float  mbuf[H];
  float* Kl = (float*)Kl4;
  float* Vl = (float*)Vl4;
  float* Gl = (float*)Gl4;
  float* Rl = (float*)Rl4;
  int*   xl = (int*)xl4;

  const int b    = blockIdx.x;
  const int tid  = threadIdx.x;
  const int lane = tid & 63;
  const int wid  = tid >> 6;               // 0..7

  // ---- stage tables + token row into LDS (512 threads) ----
  {
    const float4* Kg = (const float4*)Ktab;
    const float4* Vg = (const float4*)Vtab;
    for (int q = tid; q < VOCABN * H / 4; q += 512) {
      float4 vq = Vg[q];
      Kl4[q] = Kg[q]; Vl4[q] = vq; Rl4[q] = vq;   // R init = v (M = 0)
    }
    const int4* xg = (const int4*)(x + b * LSEQ);
    for (int q = tid; q < LSEQ / 4; q += 512) xl4[q] = xg[q];
    if (tid < VOCABN) thl[tid] = nvtab[tid];
  }
  __syncthreads();

  // ---- Gram in LDS, 8 rows per wave ----
  {
    float4 kr[16];
#pragma unroll
    for (int q = 0; q < 16; ++q) kr[q] = Kl4[lane * 16 + q];
    for (int r = 0; r < 8; ++r) {
      const int c2 = wid * 8 + r;
      const float4* kp2 = (const float4*)(Kl + c2 * H);
      float a0 = 0.f, a1 = 0.f, a2 = 0.f, a3 = 0.f;
#pragma unroll
      for (int q = 0; q < 16; ++q) {
        float4 kq = kp2[q];
        a0 = fmaf(kr[q].x, kq.x, a0);
        a1 = fmaf(kr[q].y, kq.y, a1);
        a2 = fmaf(kr[q].z, kq.z, a2);
        a3 = fmaf(kr[q].w, kq.w, a3);
      }
      Gl[c2 * H + lane] = (a0 + a1) + (a2 + a3);
    }
  }
  __syncthreads();

  // M column slice: Mw[q] holds M[lane][wid*8 + 4q .. 4q+3]  (8 cols/wave)
  float4 Mw[2];
  Mw[0] = make_float4(0.f, 0.f, 0.f, 0.f);
  Mw[1] = make_float4(0.f, 0.f, 0.f, 0.f);

  // ---- depth-3 pipeline init ----
  int   c0 = xl[0], c1 = xl[1], c2 = xl[2];
  float rv  = Rl[c0 * H + lane];
  float rvn = Rl[c1 * H + lane];
  float rb2 = Rl[c2 * H + lane];
  float th0 = thl[c0], th1 = thl[c1], th2 = thl[c2];
  float nds0 = wave_norm63(rv);
  float nds1 = wave_norm63(rvn);
  float nds2 = wave_norm63(rb2);
  float g01 = Gl[c0 * H + c1];
  float g02 = Gl[c0 * H + c2];
  // prefetched G/K row slices for c0 (8 floats each per wave)
  float4 gp0 = ((const float4*)(Gl + c0 * H))[wid * 2 + 0];
  float4 gp1 = ((const float4*)(Gl + c0 * H))[wid * 2 + 1];
  float4 kp0 = ((const float4*)(Kl + c0 * H))[wid * 2 + 0];
  float4 kp1 = ((const float4*)(Kl + c0 * H))[wid * 2 + 1];

  for (int t = 0; t < LSEQ; ++t) {
    const int i3 = (t + 3 < LSEQ) ? t + 3 : LSEQ - 1;
    const int c3 = xl[i3];
    const float th3 = thl[c3];

    float thu = __int_as_float(__builtin_amdgcn_readfirstlane(__float_as_int(th0)));

    if (nds0 > thu) {                   // block-uniform accept
      const float delta = rv;
      // in-register forwarding (bitwise == LDS RMW values)
      rvn = fmaf(-g01, delta, rvn);
      rb2 = fmaf(-g02, delta, rb2);
      nds1 = wave_norm63(rvn);          // critical for next gate (~50 cy, overlaps below)
      nds2 = wave_norm63(rb2);          // 2 steps slack
      __syncthreads();                  // read-fence: all waves' pipeline reads done
      // RMW 8 rows/wave with prefetched G slice
      float gs[8] = {gp0.x, gp0.y, gp0.z, gp0.w, gp1.x, gp1.y, gp1.z, gp1.w};
#pragma unroll
      for (int r = 0; r < 8; ++r) {
        const int cc = wid * 8 + r;
        Rl[cc * H + lane] = fmaf(-gs[r], delta, Rl[cc * H + lane]);
      }
      // M column slice with prefetched K slice (8 FMA)
      Mw[0].x = fmaf(delta, kp0.x, Mw[0].x);
      Mw[0].y = fmaf(delta, kp0.y, Mw[0].y);
      Mw[0].z = fmaf(delta, kp0.z, Mw[0].z);
      Mw[0].w = fmaf(delta, kp0.w, Mw[0].w);
      Mw[1].x = fmaf(delta, kp1.x, Mw[1].x);
      Mw[1].y = fmaf(delta, kp1.y, Mw[1].y);
      Mw[1].z = fmaf(delta, kp1.z, Mw[1].z);
      Mw[1].w = fmaf(delta, kp1.w, Mw[1].w);
      __syncthreads();                  // write-fence: visible before next reads
    }

    // bottom: pipeline advance (reads post-fence on accepts; no writers on rejects)
    float rb3  = Rl[c3 * H + lane];
    float nds3 = wave_norm63(rb3);      // 3 steps of slack
    float g01n = Gl[c1 * H + c2];
    float g02n = Gl[c1 * H + c3];
    gp0 = ((const float4*)(Gl + c1 * H))[wid * 2 + 0];
    gp1 = ((const float4*)(Gl + c1 * H))[wid * 2 + 1];
    kp0 = ((const float4*)(Kl + c1 * H))[wid * 2 + 0];
    kp1 = ((const float4*)(Kl + c1 * H))[wid * 2 + 1];

    rv = rvn; rvn = rb2; rb2 = rb3;
    nds0 = nds1; nds1 = nds2; nds2 = nds3;
    c0 = c1; c1 = c2; c2 = c3;
    th0 = th1; th1 = th2; th2 = th3;
    g01 = g01n; g02 = g02n;
  }

  // ---- reassemble M into LDS: Vl = M_T (conflict-free), Kl = M_N ----
  __syncthreads();
#pragma unroll
  for (int r = 0; r < 2; ++r) {
    const int jb = wid * 8 + r * 4;
    float4 m = Mw[r];
    Vl[(jb + 0) * H + lane] = m.x;
    Vl[(jb + 1) * H + lane] = m.y;
    Vl[(jb + 2) * H + lane] = m.z;
    Vl[(jb + 3) * H + lane] = m.w;
    Kl[lane * H + jb + 0] = m.x;
    Kl[lane * H + jb + 1] = m.y;
    Kl[lane * H + jb + 2] = m.z;
    Kl[lane * H + jb + 3] = m.w;
  }
  __syncthreads();

  // ---------------- fused readout: wave 0 (M from LDS; verbatim rounds 12-14, passed) ----------------
  if (wid == 0) {
    const int clast = xl[LSEQ - 1];
    hbuf[lane] = Htab[clast * H + lane];

    float qi = 0.f;
    for (int j = 0; j < H; ++j) qi = fmaf(Wq[lane * H + j], hbuf[j], qi);
    qbuf[lane] = qi;

    float qri = 0.f;
    for (int j = 0; j < H; ++j) qri = fmaf(Wr[lane * H + j], qbuf[j], qri);

    // slot norms^2: lane s reads M_N column s (conflict-free)
    float n2 = 0.f;
    for (int i2 = 0; i2 < H; ++i2) { float m = Kl[i2 * H + lane]; n2 = fmaf(m, m, n2); }

    // top-8 slots by norm (ties -> smaller index)
    const int KS = 8;
    int idxs[KS];
    float nloc = n2;
#pragma unroll
    for (int k = 0; k < KS; ++k) {
      float v = nloc; int idx = lane;
#pragma unroll
      for (int s = 1; s < 64; s <<= 1) {
        float ov = __shfl_xor(v, s, 64);
        int   oi = __shfl_xor(idx, s, 64);
        if (ov > v || (ov == v && oi < idx)) { v = ov; idx = oi; }
      }
      idxs[k] = idx;
      if (lane == idx) nloc = -1.f;
    }

    float sel[KS], lg[KS];
#pragma unroll
    for (int k = 0; k < KS; ++k) {
      float s = Vl[idxs[k] * H + lane];     // M_T[idx][lane]
      sel[k] = s;
      lg[k] = wave_allsum(s * qri) * 0.125f;   // / sqrt(64)
    }
    float lmax = lg[0];
#pragma unroll
    for (int k = 1; k < KS; ++k) lmax = fmaxf(lmax, lg[k]);
    float esum = 0.f, retro = 0.f;
#pragma unroll
    for (int k = 0; k < KS; ++k) {
      float e = expf(lg[k] - lmax);
      esum += e;
      retro = fmaf(e, sel[k], retro);
    }
    retro /= esum;

    // m_ctx = M q : lane i, ascending j reading M_T[j][lane] (conflict-free)
    float mc = 0.f;
    for (int j = 0; j < H; ++j) mc = fmaf(Vl[j * H + lane], qbuf[j], mc);

    float a = 1.f / (1.f + expf(-alpha[0]));
    float mixed = fmaxf(fmaf(a, retro, (1.f - a) * mc), 0.f);
    mbuf[lane] = mixed;

    float oo = bout[lane];
    for (int i2 = 0; i2 < H; ++i2) oo = fmaf(Wout[lane * H + i2], mbuf[i2], oo);
    out[b * VOCABN + lane] = oo;
  }
}

extern "C" void kernel_launch(void* const* d_in, const int* in_sizes, int n_in,
                              void* d_out, int out_size, void* d_ws, size_t ws_size,
                              hipStream_t stream) {
  const int*   x     = (const int*)d_in[0];
  const float* embed = (const float*)d_in[1];
  const float* W1    = (const float*)d_in[2];
  const float* b1    = (const float*)d_in[3];
  const float* W2    = (const float*)d_in[4];
  const float* b2    = (const float*)d_in[5];
  const float* ln_g  = (const float*)d_in[6];
  const float* ln_b  = (const float*)d_in[7];
  const float* Wk    = (const float*)d_in[8];
  const float* Wv    = (const float*)d_in[9];
  const float* Wq    = (const float*)d_in[10];
  const float* Wr    = (const float*)d_in[11];
  const float* alpha = (const float*)d_in[12];
  const float* Wout  = (const float*)d_in[13];
  const float* bout  = (const float*)d_in[14];
  float* out = (float*)d_out;

  const int B = in_sizes[0] / LSEQ;

  float* ws    = (float*)d_ws;
  float* Htab  = ws;          // 4096
  float* Ktab  = ws + 4096;   // 4096
  float* Vtab  = ws + 8192;   // 4096
  float* nvtab = ws + 12288;  // 64

  tables_kernel<<<VOCABN, 64, 0, stream>>>(embed, W1, b1, W2, b2, ln_g, ln_b,
                                           Wk, Wv, Htab, Ktab, Vtab, nvtab);
  scan_kernel<<<B, 512, 0, stream>>>(x, Htab, Ktab, Vtab, nvtab,
                                     Wq, Wr, alpha, Wout, bout, out);
}

// Round 16
// 614.990 us; speedup vs baseline: 1.3662x; 1.3662x over previous
//
#include <hip/hip_runtime.h>
#include <math.h>

#define H 64
#define VOCABN 64
#define LSEQ 2048
#define LN_EPS 1e-5f

// ---------- generic DPP add helper ----------
template <int CTRL>
__device__ __forceinline__ float dpp_add(float x) {
  return x + __int_as_float(__builtin_amdgcn_update_dpp(
      0, __float_as_int(x), CTRL, 0xF, 0xF, true));
}

// all-lane sum with broadcast result (tables / readout only)
__device__ __forceinline__ float wave_allsum(float x) {
  x = dpp_add<0xB1>(x);   // quad_perm [1,0,3,2]
  x = dpp_add<0x4E>(x);   // quad_perm [2,3,0,1]
  x = dpp_add<0x141>(x);  // row_half_mirror
  x = dpp_add<0x140>(x);  // row_mirror
  x += __shfl_xor(x, 16, 64);
  x += __shfl_xor(x, 32, 64);
  return x;
}

__device__ __forceinline__ int rdl(float v, int lane) {
  return __builtin_amdgcn_readlane(__float_as_int(v), lane);
}
__device__ __forceinline__ float rdlf(float v, int lane) {
  return __int_as_float(__builtin_amdgcn_readlane(__float_as_int(v), lane));
}

// Register-space replica of the DPP reduce_to_lane63 bracketing:
// lane63 value = (S3+S2)+(S1+S0), row S = (((hi pair)+(..))+..) high-first.
// Verified node-by-node vs row_shr:1/2/4/8 + row_bcast:15/31 chain.
// Applied per-lane over 64 registers -> nrm2 of every token simultaneously,
// BITWISE equal to the old per-token DPP norm.
__device__ __forceinline__ float norm2_tree(const float* RT) {
  float sq[64];
#pragma unroll
  for (int i = 0; i < 64; ++i) sq[i] = RT[i] * RT[i];
  float p[32];
#pragma unroll
  for (int j = 0; j < 32; ++j) p[j] = sq[2 * j + 1] + sq[2 * j];
  float q[16];
#pragma unroll
  for (int j = 0; j < 16; ++j) q[j] = p[2 * j + 1] + p[2 * j];
  float o[8];
#pragma unroll
  for (int j = 0; j < 8; ++j) o[j] = q[2 * j + 1] + q[2 * j];
  float h[4];
#pragma unroll
  for (int j = 0; j < 4; ++j) h[j] = o[2 * j + 1] + o[2 * j];
  return (h[3] + h[2]) + (h[1] + h[0]);
}

// ---------------- Kernel A: per-token tables (verbatim rounds 7-15, passed) ----------------
__global__ __launch_bounds__(64) void tables_kernel(
    const float* __restrict__ embed, const float* __restrict__ W1, const float* __restrict__ b1,
    const float* __restrict__ W2, const float* __restrict__ b2,
    const float* __restrict__ ln_g, const float* __restrict__ ln_b,
    const float* __restrict__ Wk, const float* __restrict__ Wv,
    float* __restrict__ Htab, float* __restrict__ Ktab, float* __restrict__ Vtab,
    float* __restrict__ nvtab)
{
  __shared__ float hs[H];
  __shared__ float ff1[2 * H];
  __shared__ float lns[H];
  const int c = blockIdx.x;
  const int i = threadIdx.x;

  float e = embed[c * H + i];
  hs[i] = e;
  __syncthreads();

  float r1 = b1[i], r2 = b1[i + H];
  for (int j = 0; j < H; ++j) {
    float hj = hs[j];
    r1 = fmaf(W1[i * H + j], hj, r1);
    r2 = fmaf(W1[(i + H) * H + j], hj, r2);
  }
  ff1[i]     = fmaxf(r1, 0.f);
  ff1[i + H] = fmaxf(r2, 0.f);
  __syncthreads();

  float o = b2[i];
  for (int m = 0; m < 2 * H; ++m) o = fmaf(W2[i * 2 * H + m], ff1[m], o);
  float y = e + o;

  float mu  = wave_allsum(y) * (1.f / H);
  float d   = y - mu;
  float var = wave_allsum(d * d) * (1.f / H);
  float ln  = d * (1.f / sqrtf(var + LN_EPS)) * ln_g[i] + ln_b[i];
  lns[i] = ln;
  __syncthreads();
  Htab[c * H + i] = ln;

  float k = 0.f, v = 0.f;
  for (int j = 0; j < H; ++j) {
    float lj = lns[j];
    k = fmaf(Wk[i * H + j], lj, k);
    v = fmaf(Wv[i * H + j], lj, v);
  }
  float nk = sqrtf(wave_allsum(k * k));
  Ktab[c * H + i] = k / fmaxf(nk, 1e-12f);
  Vtab[c * H + i] = v;
  float nv = sqrtf(wave_allsum(v * v));
  if (i == 0) nvtab[c] = 0.4f * nv;   // gate threshold, sqrt domain
}

// ---------------- Kernel B: single-wave register-resident scan ----------------
// One WAVE per batch element. Transposed register layout:
//   RT[i] (reg i, lane c) = residual component i of token c  (64 VGPR)
//   Mg[i] (reg i, lane j) = M[i][j]                          (64 VGPR)
//   nrm2v (lane c)        = ||R[c]||^2, tree-bracketed == DPP lane63 value
// Reject step: 2 readlane + sqrt + scalar branch. NO LDS, NO barriers.
// Accept: 64 readlane (delta) + 64 FMA RT + 64 FMA M + tree norm recompute.
// G/K rows prefetched depth-3 from the static token stream.
// Every arithmetic op is bitwise identical to rounds 10-13 (passed).
__global__ __launch_bounds__(64, 1) void scan_kernel(
    const int* __restrict__ x, const float* __restrict__ Htab,
    const float* __restrict__ Ktab, const float* __restrict__ Vtab,
    const float* __restrict__ nvtab,
    const float* __restrict__ Wq, const float* __restrict__ Wr,
    const float* __restrict__ alpha, const float* __restrict__ Wout,
    const float* __restrict__ bout, float* __restrict__ out)
{
  __shared__ float4 Kl4[VOCABN * H / 4];   // khat [c][j]  16KB
  __shared__ float  Gl[VOCABN * H];        // Gram [c][cc] 16KB
  __shared__ float4 Vp4[VOCABN * 17];      // V staged padded [c][68] (17.4KB)
  __shared__ int    xl[LSEQ];              // 8KB
  __shared__ float  Mt[VOCABN * 65];       // M^T padded: Mt[j*65+i] = M[i][j] (16.6KB)
  __shared__ float  hbuf[H];
  __shared__ float  qbuf[H];
  __shared__ float  mbuf[H];
  float* Kl = (float*)Kl4;
  float* Vp = (float*)Vp4;

  const int b    = blockIdx.x;
  const int lane = threadIdx.x;

  // ---- stage K (linear), V (pad-68 for conflict-light transposed read), x ----
  {
    const float4* Kg = (const float4*)Ktab;
    const float4* Vg = (const float4*)Vtab;
    for (int q = lane; q < VOCABN * H / 4; q += 64) {
      Kl4[q] = Kg[q];
      Vp4[(q >> 4) * 17 + (q & 15)] = Vg[q];
    }
    const int4* xg = (const int4*)(x + b * LSEQ);
    int4* xl4 = (int4*)xl;
    for (int q = lane; q < LSEQ / 4; q += 64) xl4[q] = xg[q];
  }
  float thrv = nvtab[lane];
  __syncthreads();

  // ---- Gram in LDS (same fmaf structure as rounds 10-13 -> bitwise same G) ----
  {
    float4 kr[16];
#pragma unroll
    for (int q2 = 0; q2 < 16; ++q2) kr[q2] = Kl4[lane * 16 + q2];
    for (int a = 0; a < VOCABN; ++a) {
      const float4* kp2 = (const float4*)(Kl + a * H);
      float a0 = 0.f, a1 = 0.f, a2 = 0.f, a3 = 0.f;
#pragma unroll
      for (int q2 = 0; q2 < 16; ++q2) {
        float4 kq = kp2[q2];
        a0 = fmaf(kr[q2].x, kq.x, a0);
        a1 = fmaf(kr[q2].y, kq.y, a1);
        a2 = fmaf(kr[q2].z, kq.z, a2);
        a3 = fmaf(kr[q2].w, kq.w, a3);
      }
      Gl[a * H + lane] = (a0 + a1) + (a2 + a3);
    }
  }
  __syncthreads();

  // ---- residuals + M in registers (transposed) ----
  float RT[64], Mg[64];
#pragma unroll
  for (int i = 0; i < 64; ++i) {
    RT[i] = Vp[lane * 68 + i];   // RT[i][lane=c] = v_c[i]  (M = 0)
    Mg[i] = 0.f;
  }
  float nrm2v = norm2_tree(RT);

  // ---- depth-3 prefetch pipeline over the static token stream ----
  int c0 = __builtin_amdgcn_readfirstlane(xl[0]);
  int c1 = __builtin_amdgcn_readfirstlane(xl[1]);
  int c2 = __builtin_amdgcn_readfirstlane(xl[2]);
  float gv0 = Gl[c0 * H + lane], kv0 = Kl[c0 * H + lane];
  float gv1 = Gl[c1 * H + lane], kv1 = Kl[c1 * H + lane];
  float gv2 = Gl[c2 * H + lane], kv2 = Kl[c2 * H + lane];

  for (int t = 0; t < LSEQ; ++t) {
    const int i3 = (t + 3 < LSEQ) ? t + 3 : LSEQ - 1;
    const int c3 = __builtin_amdgcn_readfirstlane(xl[i3]);
    float gv3 = Gl[c3 * H + lane];
    float kv3 = Kl[c3 * H + lane];

    float nd2 = rdlf(nrm2v, c0);
    float thc = rdlf(thrv, c0);

    if (sqrtf(nd2) > thc) {               // uniform scalar branch
#pragma unroll
      for (int i = 0; i < 64; ++i) {
        float s = rdlf(RT[i], c0);        // delta[i]
        RT[i] = fmaf(-s, gv0, RT[i]);     // == fmaf(-g, delta, R) bitwise
        Mg[i] = fmaf(s, kv0, Mg[i]);      // == fmaf(delta, k, M) bitwise
      }
      nrm2v = norm2_tree(RT);             // bitwise == DPP lane63 norms
    }

    c0 = c1; c1 = c2; c2 = c3;
    gv0 = gv1; gv1 = gv2; gv2 = gv3;
    kv0 = kv1; kv1 = kv2; kv2 = kv3;
  }

  // ---- M^T into padded LDS (conflict-free: stride 65) ----
#pragma unroll
  for (int i = 0; i < 64; ++i) Mt[lane * 65 + i] = Mg[i];
  __syncthreads();

  // ---------------- fused readout (arithmetic identical to rounds 12/13) ----------------
  const int clast = __builtin_amdgcn_readfirstlane(xl[LSEQ - 1]);
  hbuf[lane] = Htab[clast * H + lane];
  __syncthreads();

  float qi = 0.f;
  for (int j = 0; j < H; ++j) qi = fmaf(Wq[lane * H + j], hbuf[j], qi);
  qbuf[lane] = qi;
  __syncthreads();

  float qri = 0.f;
  for (int j = 0; j < H; ++j) qri = fmaf(Wr[lane * H + j], qbuf[j], qri);

  // slot norms^2 (slot s = column s of M): n2[lane] = sum_i M[i][lane]^2
  float n2 = 0.f;
#pragma unroll
  for (int i2 = 0; i2 < 64; ++i2) n2 = fmaf(Mg[i2], Mg[i2], n2);

  // top-8 slots by norm (ties -> smaller index)
  const int KS = 8;
  int idxs[KS];
  float nloc = n2;
#pragma unroll
  for (int k = 0; k < KS; ++k) {
    float v = nloc; int idx = lane;
#pragma unroll
    for (int s = 1; s < 64; s <<= 1) {
      float ov = __shfl_xor(v, s, 64);
      int   oi = __shfl_xor(idx, s, 64);
      if (ov > v || (ov == v && oi < idx)) { v = ov; idx = oi; }
    }
    idxs[k] = idx;
    if (lane == idx) nloc = -1.f;
  }

  float sel[KS], lg[KS];
#pragma unroll
  for (int k = 0; k < KS; ++k) {
    float s = Mt[idxs[k] * 65 + lane];    // M[lane][idx] = M_T[idx][lane]
    sel[k] = s;
    lg[k] = wave_allsum(s * qri) * 0.125f;   // / sqrt(64)
  }
  float lmax = lg[0];
#pragma unroll
  for (int k = 1; k < KS; ++k) lmax = fmaxf(lmax, lg[k]);
  float esum = 0.f, retro = 0.f;
#pragma unroll
  for (int k = 0; k < KS; ++k) {
    float e = expf(lg[k] - lmax);
    esum += e;
    retro = fmaf(e, sel[k], retro);
  }
  retro /= esum;

  // m_ctx = M q : mc[lane=i] = sum_j M[i][j] q[j] = sum_j Mt[j*65+lane? no: M[lane][j]]...
  // identical to rounds 12/13: mc = sum_j M_T[j][lane] * q[j] = sum_j M[lane][j] q[j]
  float mc = 0.f;
  for (int j = 0; j < H; ++j) mc = fmaf(Mt[j * 65 + lane], qbuf[j], mc);

  float a = 1.f / (1.f + expf(-alpha[0]));
  float mixed = fmaxf(fmaf(a, retro, (1.f - a) * mc), 0.f);
  mbuf[lane] = mixed;
  __syncthreads();

  float oo = bout[lane];
  for (int i2 = 0; i2 < H; ++i2) oo = fmaf(Wout[lane * H + i2], mbuf[i2], oo);
  out[b * VOCABN + lane] = oo;
}

extern "C" void kernel_launch(void* const* d_in, const int* in_sizes, int n_in,
                              void* d_out, int out_size, void* d_ws, size_t ws_size,
                              hipStream_t stream) {
  const int*   x     = (const int*)d_in[0];
  const float* embed = (const float*)d_in[1];
  const float* W1    = (const float*)d_in[2];
  const float* b1    = (const float*)d_in[3];
  const float* W2    = (const float*)d_in[4];
  const float* b2    = (const float*)d_in[5];
  const float* ln_g  = (const float*)d_in[6];
  const float* ln_b  = (const float*)d_in[7];
  const float* Wk    = (const float*)d_in[8];
  const float* Wv    = (const float*)d_in[9];
  const float* Wq    = (const float*)d_in[10];
  const float* Wr    = (const float*)d_in[11];
  const float* alpha = (const float*)d_in[12];
  const float* Wout  = (const float*)d_in[13];
  const float* bout  = (const float*)d_in[14];
  float* out = (float*)d_out;

  const int B = in_sizes[0] / LSEQ;

  float* ws    = (float*)d_ws;
  float* Htab  = ws;          // 4096
  float* Ktab  = ws + 4096;   // 4096
  float* Vtab  = ws + 8192;   // 4096
  float* nvtab = ws + 12288;  // 64

  tables_kernel<<<VOCABN, 64, 0, stream>>>(embed, W1, b1, W2, b2, ln_g, ln_b,
                                           Wk, Wv, Htab, Ktab, Vtab, nvtab);
  scan_kernel<<<B, 64, 0, stream>>>(x, Htab, Ktab, Vtab, nvtab,
                                    Wq, Wr, alpha, Wout, bout, out);
}